// Round 8
// baseline (101.062 us; speedup 1.0000x reference)
//
#include <hip/hip_runtime.h>

#define B 64
#define N 1024
#define E 16384
#define WPR 32          // words per adjacency row = N/32
#define NITER 5
#define CSR_SLOTS (E + N)   // even-aligned per-node alloc: <=1 pad slot/node
#define MAXP 20             // pair-words cached in registers (deg<=40; LDS fallback beyond)
#define SENT_PAIR 0x04000400u   // (N<<16)|N : both halves index s_lab[N]==0
#define CAP 8               // grp2 slots per bucket (overflow -> slow path)
#define GSTRIDE 9           // grp2 row stride (9 coprime 32 => bank-conflict-free)
#define NT 512              // threads/block; 2 nodes per thread

// ---- workspace layout (bytes) ---- (NO memset: feats/diag fully stored
// before any read; harness 0xAA poison harmless)
#define FEATS_OFF 0
#define DIAG_OFF  ((size_t)B * N * 4)

// R30: 512 threads x 2 nodes/thread (nodes 2t,2t+1). R29 showed barrier
// COUNT marginal is ~0.1us; the remaining lever is wave count: 8 waves
// instead of 16 halves barrier arrival/drain and per-segment LDS-pipe
// occupancy-per-wave, combines shrink 16->8 partials, and per-thread ILP
// doubles (2 nodes' gathers interleave). Adjacent node pairs keep every
// scan as a pair-sum + wave-scan + 8-combine; per-node LDS init becomes
// int2. All R29 structure retained: 5-barrier fast path, stride-9 grp2,
// no-A3 barrier, sentinel-padded unconditional gathers.
__global__ void __launch_bounds__(NT) wl_mega_k(const int* __restrict__ src,
                                                const int* __restrict__ dstp,
                                                const int* __restrict__ lab0,
                                                const float* __restrict__ hw,
                                                unsigned int* __restrict__ feats,
                                                float* __restrict__ diag) {
    __shared__ union {
        unsigned int chunk[N * WPR];                // Phase A1: 128KB full bitmask
        struct {
            unsigned short nbr[CSR_SLOTS];          // Phase A2/B: 34816B CSR (self-read only)
            struct {                                // Phase B: rank arrays
                int hist[N];
                int scan[N];
                float grp[N];                       // slow-path ordered groups
                int flag[N];
                float grp2[N * GSTRIDE];            // fast-path groups, 36KB
            } pb;
        } s;
    } u;
    __shared__ int s_lab[N + 2];                    // +sentinel slot (=0)
    __shared__ unsigned int s_feats[N];
    __shared__ int s_wsum[8];
    __shared__ int s_kp[8];
    __shared__ float s_mn[8], s_mx[8];
    __shared__ int s_anytie;
    __shared__ int s_ovf;
    int b = blockIdx.x, t = threadIdx.x;
    int lane = t & 63, w = t >> 6;                  // w in 0..7
    int n0 = t * 2, n1 = t * 2 + 1;

    // ---- Phase A0: edge batch1 loads first (L3 latency overlaps LDS zero) ----
    const int* sg = src + (size_t)b * E;
    const int* dg_ = dstp + (size_t)b * E;
    int es[16], ed[16];
#pragma unroll
    for (int k = 0; k < 16; ++k) {                  // coalesced
        es[k] = sg[t + k * NT];
        ed[k] = dg_[t + k * NT];
    }
    int2 l0p = *(const int2*)(lab0 + (size_t)b * N + n0);
    float w0 = hw[0], w1 = hw[1];
    // zero 128KB bitmask while loads are in flight (16 uint4/thread)
#pragma unroll
    for (int k = 0; k < 16; ++k)
        ((uint4*)u.chunk)[t + k * NT] = make_uint4(0, 0, 0, 0);
    *(int2*)&s_lab[n0] = l0p;
    ((uint2*)s_feats)[t] = make_uint2(0u, 0u);
    if (t == 0) { s_lab[N] = 0; s_anytie = 0; s_ovf = 0; }
    __syncthreads();                                        // P0
    // init label bincount (labels < 16) via ballot, both node sets
#pragma unroll
    for (int v = 0; v < 16; ++v) {
        unsigned long long m0 = __ballot(l0p.x == v);
        unsigned long long m1 = __ballot(l0p.y == v);
        if (lane == v) {
            int c = __popcll(m0) + __popcll(m1);
            if (c) atomicAdd(&s_feats[v], (unsigned)c);
        }
    }

    // ---- Phase A1: bitmask scatter (swizzled); batch2 loads overlap ----
    int es2[16], ed2[16];
#pragma unroll
    for (int k = 0; k < 16; ++k) {
        es2[k] = sg[8192 + t + k * NT];
        ed2[k] = dg_[8192 + t + k * NT];
    }
#pragma unroll
    for (int k = 0; k < 16; ++k) {
        int wlog = ed[k] >> 5;                      // logical word 0..31
        int g = wlog >> 2;                          // logical group 0..7
        int p = (g + es[k]) & 7;                    // swizzled slot
        atomicOr(&u.chunk[es[k] * WPR + p * 4 + (wlog & 3)], 1u << (ed[k] & 31));
    }
#pragma unroll
    for (int k = 0; k < 16; ++k) {
        int wlog = ed2[k] >> 5;
        int g = wlog >> 2;
        int p = (g + es2[k]) & 7;
        atomicOr(&u.chunk[es2[k] * WPR + p * 4 + (wlog & 3)], 1u << (ed2[k] & 31));
    }
    __syncthreads();                                        // C2
    uint4 r0[8], r1[8];
    {
        const uint4* rowA = (const uint4*)(u.chunk + n0 * WPR);
        const uint4* rowB = (const uint4*)(u.chunk + n1 * WPR);
#pragma unroll
        for (int g = 0; g < 8; ++g) r0[g] = rowA[(g + n0) & 7];  // <=2-way (free)
#pragma unroll
        for (int g = 0; g < 8; ++g) r1[g] = rowB[(g + n1) & 7];
    }
    __syncthreads();                                        // C3: chunk reusable

    // ---- Phase A2: deg/alloc/K/CSR starts (pair scan) + pack ----
    int dg0 = 0, dg1 = 0;
#pragma unroll
    for (int k = 0; k < 8; ++k) {
        dg0 += __popc(r0[k].x) + __popc(r0[k].y) + __popc(r0[k].z) + __popc(r0[k].w);
        dg1 += __popc(r1[k].x) + __popc(r1[k].y) + __popc(r1[k].z) + __popc(r1[k].w);
    }
    int alloc0 = (dg0 + 1) & ~1, alloc1 = (dg1 + 1) & ~1;
    int ps = alloc0 + alloc1;                       // pair sum
    int f = ps;                                     // wave inclusive scan
#pragma unroll
    for (int d2 = 1; d2 < 64; d2 <<= 1) {
        int v = __shfl_up(f, d2);
        if (lane >= d2) f += v;
    }
    int km = max(dg0, dg1);
#pragma unroll
    for (int o = 32; o > 0; o >>= 1) km = max(km, __shfl_down(km, o));
    if (lane == 63) s_wsum[w] = f;
    if (lane == 0)  s_kp[w] = km;
    __syncthreads();                                        // A1
    // all-wave redundant combine: wave-exclusive base + block K, in registers
    float Kf;
    int start0, start1;
    {
        int vv = ((lane & 7) < w) ? s_wsum[lane & 7] : 0;
#pragma unroll
        for (int m2 = 1; m2 < 8; m2 <<= 1) vv += __shfl_xor(vv, m2);
        start0 = (f - ps) + vv;                     // even => u32-aligned
        start1 = start0 + alloc0;
        int kk = s_kp[lane & 7];
#pragma unroll
        for (int m2 = 4; m2 >= 1; m2 >>= 1) kk = max(kk, __shfl_xor(kk, m2));
        Kf = (float)kk;
    }
    ((int2*)u.s.pb.hist)[t] = make_int2(0, 0);      // aliases chunk: re-init
    ((int2*)u.s.pb.flag)[t] = make_int2(0, 0);

    // pack both rows' set bits ONCE -> u16 list; pad odd deg with sentinel N
    {
        int idx = start0;
#pragma unroll
        for (int k = 0; k < 8; ++k) {
            unsigned int wv[4] = { r0[k].x, r0[k].y, r0[k].z, r0[k].w };
#pragma unroll
            for (int c2 = 0; c2 < 4; ++c2) {
                unsigned int word = wv[c2];
                int bb = (k * 4 + c2) << 5;
                while (word) {
                    int j = __ffs(word) - 1;
                    word &= word - 1;
                    u.s.nbr[idx++] = (unsigned short)(bb + j);
                }
            }
        }
        if (dg0 & 1) u.s.nbr[idx] = (unsigned short)N;
        idx = start1;
#pragma unroll
        for (int k = 0; k < 8; ++k) {
            unsigned int wv[4] = { r1[k].x, r1[k].y, r1[k].z, r1[k].w };
#pragma unroll
            for (int c2 = 0; c2 < 4; ++c2) {
                unsigned int word = wv[c2];
                int bb = (k * 4 + c2) << 5;
                while (word) {
                    int j = __ffs(word) - 1;
                    word &= word - 1;
                    u.s.nbr[idx++] = (unsigned short)(bb + j);
                }
            }
        }
        if (dg1 & 1) u.s.nbr[idx] = (unsigned short)N;
    }
    // NO barrier: pw preload reads only this thread's own nbr bytes (same-
    // wave DS ops serviced in order); fence stops compiler reordering.
    asm volatile("" ::: "memory");

    int vpairs0 = alloc0 >> 1, vpairs1 = alloc1 >> 1;
    int vps0 = start0 >> 1, vps1 = start1 >> 1;
    int lr0 = l0p.x, lr1 = l0p.y;
    const unsigned int* nbr32 = (const unsigned int*)u.s.nbr;
    unsigned int pw0[MAXP], pw1[MAXP];
#pragma unroll
    for (int k = 0; k < MAXP; ++k) {
        pw0[k] = (k < vpairs0) ? nbr32[vps0 + k] : SENT_PAIR;
        pw1[k] = (k < vpairs1) ? nbr32[vps1 + k] : SENT_PAIR;
    }

    // ---- Phase B: 5 WL iterations ----
    int nfast = 0;                                  // fast-path feats counter
    for (int it = 0; it < NITER; ++it) {
        int ss0 = 0, ss1 = 0;
#pragma unroll
        for (int k = 0; k < MAXP; ++k) {            // unconditional, interleaved
            unsigned int pa = pw0[k], pb2 = pw1[k];
            ss0 += s_lab[pa & 0xFFFFu] + s_lab[pa >> 16];
            ss1 += s_lab[pb2 & 0xFFFFu] + s_lab[pb2 >> 16];
        }
        for (int k = MAXP; k < vpairs0; ++k) {      // rare high-deg fallback
            unsigned int pr = nbr32[vps0 + k];
            ss0 += s_lab[pr & 0xFFFFu] + s_lab[pr >> 16];
        }
        for (int k = MAXP; k < vpairs1; ++k) {
            unsigned int pr = nbr32[vps1 + k];
            ss1 += s_lab[pr & 0xFFFFu] + s_lab[pr >> 16];
        }
        float h0 = __fadd_rn(__fmul_rn(__fmul_rn(Kf, w0), (float)lr0),
                             __fmul_rn(w1, __fsub_rn(__fadd_rn((float)ss0, (float)dg0), Kf)));
        float h1 = __fadd_rn(__fmul_rn(__fmul_rn(Kf, w0), (float)lr1),
                             __fmul_rn(w1, __fsub_rn(__fadd_rn((float)ss1, (float)dg1), Kf)));

        float mn = fminf(h0, h1), mx = fmaxf(h0, h1);
#pragma unroll
        for (int o = 32; o > 0; o >>= 1) {
            mn = fminf(mn, __shfl_down(mn, o));
            mx = fmaxf(mx, __shfl_down(mx, o));
        }
        if (lane == 0) { s_mn[w] = mn; s_mx[w] = mx; }
        __syncthreads();                                    // B1
        // all-wave redundant min/max combine -> registers
        float fmn, span;
        {
            float a = s_mn[lane & 7];
            float cmx = s_mx[lane & 7];
#pragma unroll
            for (int m2 = 4; m2 >= 1; m2 >>= 1) {
                a = fminf(a, __shfl_xor(a, m2));
                cmx = fmaxf(cmx, __shfl_xor(cmx, m2));
            }
            fmn = a;
            span = cmx - a;
        }
        float scale = (span > 0.f) ? (1023.0f / span) : 0.f;
        int bk0 = min((int)((h0 - fmn) * scale), 1023);     // order-preserving
        int bk1 = min((int)((h1 - fmn) * scale), 1023);
        int off0 = atomicAdd(&u.s.pb.hist[bk0], 1);
        if (off0 < CAP) u.s.pb.grp2[bk0 * GSTRIDE + off0] = h0;
        else s_ovf = 1;
        int off1 = atomicAdd(&u.s.pb.hist[bk1], 1);
        if (off1 < CAP) u.s.pb.grp2[bk1 * GSTRIDE + off1] = h1;
        else s_ovf = 1;
        __syncthreads();                                    // B3

        int ovf = s_ovf;                            // uniform post-B3
        int cnt0 = u.s.pb.hist[bk0];
        int cnt1 = u.s.pb.hist[bk1];
        int c0 = 0, eq0 = 0, c1 = 0, eq1 = 0;
        if (!ovf) {                                 // conflict-free (stride 9)
            for (int j = 0; j < cnt0; ++j) {
                float g = u.s.pb.grp2[bk0 * GSTRIDE + j];
                c0 += (g < h0);
                eq0 += (g == h0);
            }
            for (int j = 0; j < cnt1; ++j) {
                float g = u.s.pb.grp2[bk1 * GSTRIDE + j];
                c1 += (g < h1);
                eq1 += (g == h1);
            }
        }
        int2 hp = ((int2*)u.s.pb.hist)[t];          // pair for the scan
        int hs = hp.x + hp.y;
        f = hs;
#pragma unroll
        for (int d2 = 1; d2 < 64; d2 <<= 1) {
            int v = __shfl_up(f, d2);
            if (lane >= d2) f += v;
        }
        if (lane == 63) s_wsum[w] = f;
        __syncthreads();                                    // B4
        {   // all-wave redundant exclusive wave base -> register
            int vv = ((lane & 7) < w) ? s_wsum[lane & 7] : 0;
#pragma unroll
            for (int m2 = 1; m2 < 8; m2 <<= 1) vv += __shfl_xor(vv, m2);
            u.s.pb.scan[n0] = vv + f - hs + hp.x;   // inclusive at n0
            u.s.pb.scan[n1] = vv + f;               // inclusive at n1
        }
        ((int2*)u.s.pb.hist)[t] = make_int2(0, 0);  // cnt latched pre-B4
        if (t == 0) s_ovf = 0;                      // ovf latched pre-B4
        __syncthreads();                                    // B6

        int cr0, cr1;
        if (!ovf) {
            cr0 = (u.s.pb.scan[bk0] - cnt0) + c0;   // dense rank iff no ties
            cr1 = (u.s.pb.scan[bk1] - cnt1) + c1;
        } else {                        // slow path: scan-ordered groups
            int bs0 = u.s.pb.scan[bk0] - cnt0;
            int bs1 = u.s.pb.scan[bk1] - cnt1;
            u.s.pb.grp[bs0 + off0] = h0;
            u.s.pb.grp[bs1 + off1] = h1;
            __syncthreads();                                // B7 (rare)
            cr0 = bs0; eq0 = 0;
            for (int k = bs0; k < bs0 + cnt0; ++k) {
                float g = u.s.pb.grp[k];
                cr0 += (g < h0);
                eq0 += (g == h0);
            }
            cr1 = bs1; eq1 = 0;
            for (int k = bs1; k < bs1 + cnt1; ++k) {
                float g = u.s.pb.grp[k];
                cr1 += (g < h1);
                eq1 += (g == h1);
            }
        }
        if ((eq0 > 1) || (eq1 > 1)) s_anytie = it + 1;  // stale iters self-invalidate
        s_lab[n0] = cr0;                // optimistic fast-path ranks
        s_lab[n1] = cr1;
        __syncthreads();                                    // B9
        if (s_anytie == it + 1) {       // rare: dense-rank repair pass
            u.s.pb.flag[cr0] = 1;       // class start (same class -> same cr)
            u.s.pb.flag[cr1] = 1;
            __syncthreads();                                // T1
            int2 fp = ((int2*)u.s.pb.flag)[t];
            int fs = fp.x + fp.y;
            int f2 = fs;
#pragma unroll
            for (int d2 = 1; d2 < 64; d2 <<= 1) {
                int v = __shfl_up(f2, d2);
                if (lane >= d2) f2 += v;
            }
            if (lane == 63) s_wsum[w] = f2;
            __syncthreads();                                // T2
            {
                int vv = ((lane & 7) < w) ? s_wsum[lane & 7] : 0;
#pragma unroll
                for (int m2 = 1; m2 < 8; m2 <<= 1) vv += __shfl_xor(vv, m2);
                u.s.pb.scan[n0] = vv + f2 - fs + fp.x;
                u.s.pb.scan[n1] = vv + f2;
            }
            ((int2*)u.s.pb.flag)[t] = make_int2(0, 0);  // own flags consumed
            __syncthreads();                                // T4
            int rank0 = u.s.pb.scan[cr0] - 1;
            int rank1 = u.s.pb.scan[cr1] - 1;
            s_lab[n0] = rank0;
            s_lab[n1] = rank1;
            lr0 = rank0;
            lr1 = rank1;
            atomicAdd(&s_feats[rank0], 1u);
            atomicAdd(&s_feats[rank1], 1u);
            __syncthreads();                                // T5: labels visible
        } else {
            lr0 = cr0;
            lr1 = cr1;
            ++nfast;                    // permutation => every bin +1
        }
    }

    // ---- Phase C: feats out + fused diag[b] (int exact) ----
    unsigned int fv0 = s_feats[n0] + (unsigned)nfast;
    unsigned int fv1 = s_feats[n1] + (unsigned)nfast;
    *(uint2*)(feats + (size_t)b * N + n0) = make_uint2(fv0, fv1);
    int sq = (int)(fv0 * fv0 + fv1 * fv1);
#pragma unroll
    for (int o = 32; o > 0; o >>= 1) sq += __shfl_down(sq, o);
    if (lane == 0) s_wsum[w] = sq;
    __syncthreads();
    if (t == 0) {
        int tot = 0;
#pragma unroll
        for (int k = 0; k < 8; ++k) tot += s_wsum[k];
        diag[b] = (float)tot;
    }
}

// gram+normalize fused: one block per row i; f_i staged in LDS; int dots
// exact. 1024 threads, 16 waves x 4 j's each (serial chain 4 iterations).
__global__ void __launch_bounds__(1024) gram_k(const unsigned int* __restrict__ feats,
                                               const float* __restrict__ diag,
                                               float* __restrict__ out) {
    __shared__ unsigned int s_fi[N];
    int i = blockIdx.x, t = threadIdx.x;
    int lane = t & 63, w = t >> 6;
    if (t < 256)
        ((uint4*)s_fi)[t] = ((const uint4*)(feats + (size_t)i * N))[t];
    __syncthreads();
    float di = diag[i];
#pragma unroll
    for (int jj = 0; jj < 4; ++jj) {
        int j = w * 4 + jj;
        const uint4* fj = (const uint4*)(feats + (size_t)j * N);
        const uint4* fi = (const uint4*)s_fi;
        int s = 0;
#pragma unroll
        for (int k = 0; k < 4; ++k) {
            uint4 vb = fj[lane + k * 64];
            uint4 va = fi[lane + k * 64];
            s += (int)(va.x * vb.x) + (int)(va.y * vb.y)
               + (int)(va.z * vb.z) + (int)(va.w * vb.w);
        }
#pragma unroll
        for (int off = 32; off > 0; off >>= 1) s += __shfl_down(s, off);
        if (lane == 0) out[i * B + j] = (float)s / sqrtf(di * diag[j]);
    }
}

extern "C" void kernel_launch(void* const* d_in, const int* in_sizes, int n_in,
                              void* d_out, int out_size, void* d_ws, size_t ws_size,
                              hipStream_t stream) {
    const int*   esrc = (const int*)d_in[0];
    const int*   edst = (const int*)d_in[1];
    const int*   lab0 = (const int*)d_in[2];
    const float* hw   = (const float*)d_in[3];

    char* ws = (char*)d_ws;
    unsigned int* feats = (unsigned int*)(ws + FEATS_OFF);
    float*        diag  = (float*)(ws + DIAG_OFF);

    wl_mega_k<<<B, NT, 0, stream>>>(esrc, edst, lab0, hw, feats, diag);
    gram_k<<<B, 1024, 0, stream>>>(feats, diag, (float*)d_out);
}

// Round 9
// 91.932 us; speedup vs baseline: 1.0993x; 1.0993x over previous
//
#include <hip/hip_runtime.h>

#define B 64
#define N 1024
#define E 16384
#define WPR 32          // words per adjacency row = N/32
#define NITER 5
#define CSR_SLOTS (E + N)   // even-aligned per-node alloc: <=1 pad slot/node
#define MAXP 20             // pair-words cached in registers (deg<=40; LDS fallback beyond)
#define SENT_PAIR 0x04000400u   // (N<<16)|N : both halves index s_lab[N]==0
#define CAP 8               // grp2 slots per bucket (overflow -> slow path)
#define GSTRIDE 9           // grp2 row stride (9 coprime 32 => bank-conflict-free)

// ---- workspace layout (bytes) ---- (NO memset: feats/diag fully stored
// before any read; harness 0xAA poison harmless)
#define FEATS_OFF 0
#define DIAG_OFF  ((size_t)B * N * 4)

// R31: shuffle chains -> DPP (VALU). HIP __shfl_* lowers to ds_bpermute
// (DS pipe, ~30-40cyc chained latency, shares the LDS pipe with gathers).
// Each Phase-B segment carries a serial 6-deep shfl scan + 4-deep combine
// on the critical path. gfx9-lineage DPP does a 64-lane inclusive scan in
// 6 VALU ops (row_shr:1/2/4/8 + row_bcast:15/31) and a 16-lane reduce in
// 4 (quad_perm/mirror) via __builtin_amdgcn_update_dpp (old=0 = identity).
// Float min/max run in monotone biased-uint key space so DPP's 0-fill is
// the identity; unbias after the combine. R30's 512-thread variant
// REVERTED (+2.8us: too little TLP). Base = R29 (best, 98.28).
__device__ __forceinline__ int dpp_scan_add(int x) {    // 64-lane inclusive sum
    x += __builtin_amdgcn_update_dpp(0, x, 0x111, 0xf, 0xf, true); // row_shr:1
    x += __builtin_amdgcn_update_dpp(0, x, 0x112, 0xf, 0xf, true); // row_shr:2
    x += __builtin_amdgcn_update_dpp(0, x, 0x114, 0xf, 0xf, true); // row_shr:4
    x += __builtin_amdgcn_update_dpp(0, x, 0x118, 0xf, 0xf, true); // row_shr:8
    x += __builtin_amdgcn_update_dpp(0, x, 0x142, 0xa, 0xf, true); // bcast15 -> rows 1,3
    x += __builtin_amdgcn_update_dpp(0, x, 0x143, 0xc, 0xf, true); // bcast31 -> rows 2,3
    return x;                                            // lane63 = total
}
__device__ __forceinline__ unsigned dpp_scan_maxu(unsigned x) { // lane63 = wave max
    unsigned y;
    y = (unsigned)__builtin_amdgcn_update_dpp(0, (int)x, 0x111, 0xf, 0xf, true); x = x > y ? x : y;
    y = (unsigned)__builtin_amdgcn_update_dpp(0, (int)x, 0x112, 0xf, 0xf, true); x = x > y ? x : y;
    y = (unsigned)__builtin_amdgcn_update_dpp(0, (int)x, 0x114, 0xf, 0xf, true); x = x > y ? x : y;
    y = (unsigned)__builtin_amdgcn_update_dpp(0, (int)x, 0x118, 0xf, 0xf, true); x = x > y ? x : y;
    y = (unsigned)__builtin_amdgcn_update_dpp(0, (int)x, 0x142, 0xa, 0xf, true); x = x > y ? x : y;
    y = (unsigned)__builtin_amdgcn_update_dpp(0, (int)x, 0x143, 0xc, 0xf, true); x = x > y ? x : y;
    return x;
}
__device__ __forceinline__ int dpp_red16_add(int x) {   // every lane: sum of its 16-group
    x += __builtin_amdgcn_update_dpp(0, x, 0xB1, 0xf, 0xf, true);  // quad_perm [1,0,3,2]
    x += __builtin_amdgcn_update_dpp(0, x, 0x4E, 0xf, 0xf, true);  // quad_perm [2,3,0,1]
    x += __builtin_amdgcn_update_dpp(0, x, 0x141, 0xf, 0xf, true); // row_half_mirror
    x += __builtin_amdgcn_update_dpp(0, x, 0x140, 0xf, 0xf, true); // row_mirror
    return x;
}
__device__ __forceinline__ unsigned dpp_red16_maxu(unsigned x) {
    unsigned y;
    y = (unsigned)__builtin_amdgcn_update_dpp(0, (int)x, 0xB1, 0xf, 0xf, true);  x = x > y ? x : y;
    y = (unsigned)__builtin_amdgcn_update_dpp(0, (int)x, 0x4E, 0xf, 0xf, true);  x = x > y ? x : y;
    y = (unsigned)__builtin_amdgcn_update_dpp(0, (int)x, 0x141, 0xf, 0xf, true); x = x > y ? x : y;
    y = (unsigned)__builtin_amdgcn_update_dpp(0, (int)x, 0x140, 0xf, 0xf, true); x = x > y ? x : y;
    return x;
}
// monotone float<->uint total-order keys (no NaNs in this kernel)
__device__ __forceinline__ unsigned fkey(float h) {
    unsigned s = __float_as_uint(h);
    return ((int)s < 0) ? ~s : (s | 0x80000000u);
}
__device__ __forceinline__ float ubf(unsigned u) {
    unsigned s = (u & 0x80000000u) ? (u & 0x7FFFFFFFu) : ~u;
    return __uint_as_float(s);
}

__global__ void __launch_bounds__(1024) wl_mega_k(const int* __restrict__ src,
                                                  const int* __restrict__ dstp,
                                                  const int* __restrict__ lab0,
                                                  const float* __restrict__ hw,
                                                  unsigned int* __restrict__ feats,
                                                  float* __restrict__ diag) {
    __shared__ union {
        unsigned int chunk[N * WPR];                // Phase A1: 128KB full bitmask
        struct {
            unsigned short nbr[CSR_SLOTS];          // Phase A2/B: 34816B CSR (self-read only)
            struct {                                // Phase B: rank arrays
                int hist[N];
                int scan[N];
                float grp[N];                       // slow-path ordered groups
                int flag[N];
                float grp2[N * GSTRIDE];            // fast-path groups, 36KB
            } pb;
        } s;
    } u;
    __shared__ int s_lab[N + 2];                    // +sentinel slot (=0)
    __shared__ unsigned int s_feats[N];
    __shared__ int s_wsum[16];
    __shared__ int s_kp[16];
    __shared__ unsigned s_mnk[16], s_mxk[16];       // biased-uint min/max keys
    __shared__ int s_anytie;
    __shared__ int s_ovf;
    int b = blockIdx.x, t = threadIdx.x;
    int lane = t & 63, w = t >> 6;

    // ---- Phase A0: edge loads first (L3 latency overlaps LDS zero) ----
    const int* sg = src + (size_t)b * E;
    const int* dg_ = dstp + (size_t)b * E;
    int es[16], ed[16];
#pragma unroll
    for (int k = 0; k < 16; ++k) {                  // coalesced, 1 block/graph
        es[k] = sg[t + k * 1024];
        ed[k] = dg_[t + k * 1024];
    }
    int l0 = lab0[(size_t)b * N + t];
    float w0 = hw[0], w1 = hw[1];
    // zero 128KB bitmask while loads are in flight
#pragma unroll
    for (int k = 0; k < 8; ++k)
        ((uint4*)u.chunk)[t + k * 1024] = make_uint4(0, 0, 0, 0);
    s_lab[t] = l0;
    s_feats[t] = 0;
    if (t == 0) { s_lab[N] = 0; s_anytie = 0; s_ovf = 0; }
    __syncthreads();                                        // P0
    // init label bincount (labels < 16) via ballot
#pragma unroll
    for (int v = 0; v < 16; ++v) {
        unsigned long long m = __ballot(l0 == v);
        if (lane == v) {
            int c = __popcll(m);
            if (c) atomicAdd(&s_feats[v], (unsigned)c);
        }
    }

    // ---- Phase A1: bitmask scatter (swizzled), row -> r[8] ----
#pragma unroll
    for (int k = 0; k < 16; ++k) {
        int wlog = ed[k] >> 5;                      // logical word 0..31
        int g = wlog >> 2;                          // logical group 0..7
        int p = (g + es[k]) & 7;                    // swizzled slot
        atomicOr(&u.chunk[es[k] * WPR + p * 4 + (wlog & 3)], 1u << (ed[k] & 31));
    }
    __syncthreads();                                        // C2
    uint4 r[8];
    {
        const uint4* row4 = (const uint4*)(u.chunk + t * WPR);
#pragma unroll
        for (int g = 0; g < 8; ++g)
            r[g] = row4[(g + t) & 7];               // conflict-free (swizzled)
    }
    __syncthreads();                                        // C3: chunk reusable

    // ---- Phase A2: deg/alloc/K/CSR starts + pack ----
    int dg = 0;
#pragma unroll
    for (int k = 0; k < 8; ++k)
        dg += __popc(r[k].x) + __popc(r[k].y) + __popc(r[k].z) + __popc(r[k].w);
    int alloc = (dg + 1) & ~1;                      // even per-node CSR alloc

    int f = dpp_scan_add(alloc);                    // wave inclusive scan (VALU)
    unsigned kmw = dpp_scan_maxu((unsigned)dg);     // wave max deg (VALU)
    if (lane == 63) { s_wsum[w] = f; s_kp[w] = (int)kmw; }
    __syncthreads();                                        // A1
    // all-wave redundant combine: wave-exclusive base + block K, in registers
    float Kf;
    int start;
    {
        int vv = ((lane & 15) < w) ? s_wsum[lane & 15] : 0;
        vv = dpp_red16_add(vv);
        start = (f - alloc) + vv;                   // even => u32-aligned
        unsigned kk = dpp_red16_maxu((unsigned)s_kp[lane & 15]);
        Kf = (float)kk;
    }
    u.s.pb.hist[t] = 0;                             // aliases chunk: re-init
    u.s.pb.flag[t] = 0;

    // pack own row's set bits ONCE -> u16 list; pad odd deg with sentinel N
    {
        int idx = start;
#pragma unroll
        for (int k = 0; k < 8; ++k) {
            unsigned int wv[4] = { r[k].x, r[k].y, r[k].z, r[k].w };
#pragma unroll
            for (int c2 = 0; c2 < 4; ++c2) {
                unsigned int word = wv[c2];
                int bb = (k * 4 + c2) << 5;
                while (word) {
                    int j = __ffs(word) - 1;
                    word &= word - 1;
                    u.s.nbr[idx++] = (unsigned short)(bb + j);
                }
            }
        }
        if (dg & 1) u.s.nbr[idx] = (unsigned short)N;   // sentinel -> adds 0
    }
    // NO barrier: pw preload reads only this thread's own nbr bytes (same-
    // wave DS ops are serviced in order); fence stops compiler reordering.
    asm volatile("" ::: "memory");

    int vdeg = dg;
    int vpstart = start >> 1;
    int vpairs = alloc >> 1;
    int lab_reg = l0;
    const unsigned int* nbr32 = (const unsigned int*)u.s.nbr;
    // iteration-invariant pair-words -> registers; sentinel-pad to MAXP so
    // the hot loop needs NO predication (sentinel reads broadcast s_lab[N]=0)
    unsigned int pw[MAXP];
#pragma unroll
    for (int k = 0; k < MAXP; ++k)
        pw[k] = (k < vpairs) ? nbr32[vpstart + k] : SENT_PAIR;

    // ---- Phase B: 5 WL iterations ----
    int nfast = 0;                                  // fast-path feats counter
    for (int it = 0; it < NITER; ++it) {
        int ssum = 0;
#pragma unroll
        for (int k = 0; k < MAXP; ++k) {            // unconditional: 40 gathers
            unsigned int pr = pw[k];
            ssum += s_lab[pr & 0xFFFFu] + s_lab[pr >> 16];
        }
        for (int k = MAXP; k < vpairs; ++k) {       // rare high-deg fallback
            unsigned int pr = nbr32[vpstart + k];
            ssum += s_lab[pr & 0xFFFFu] + s_lab[pr >> 16];
        }
        float t1 = __fmul_rn(__fmul_rn(Kf, w0), (float)lab_reg);
        float t2 = __fmul_rn(w1, __fsub_rn(__fadd_rn((float)ssum, (float)vdeg), Kf));
        float h  = __fadd_rn(t1, t2);

        // wave min/max via DPP max-scan on biased keys (VALU, no DS)
        unsigned uk = fkey(h);
        unsigned kx = dpp_scan_maxu(uk);
        unsigned kn = dpp_scan_maxu(~uk);
        if (lane == 63) { s_mnk[w] = kn; s_mxk[w] = kx; }
        __syncthreads();                                    // B1
        // all-wave redundant combine -> registers (no 2nd barrier)
        float fmn, span;
        {
            unsigned a = dpp_red16_maxu(s_mnk[lane & 15]);  // max of ~key = min
            unsigned cx = dpp_red16_maxu(s_mxk[lane & 15]);
            fmn = ubf(~a);
            span = ubf(cx) - fmn;
        }
        float scale = (span > 0.f) ? (1023.0f / span) : 0.f;
        int bucket = min((int)((h - fmn) * scale), 1023);   // order-preserving
        int off_in = atomicAdd(&u.s.pb.hist[bucket], 1);
        if (off_in < CAP) u.s.pb.grp2[bucket * GSTRIDE + off_in] = h; // B3 covers
        else s_ovf = 1;                                               // rare
        __syncthreads();                                    // B3

        int ovf = s_ovf;                            // uniform post-B3
        int cnt = u.s.pb.hist[bucket];              // final bucket count (reg)
        int c_in = 0, eq = 0;
        if (!ovf) {                                 // conflict-free (stride 9)
            for (int j = 0; j < cnt; ++j) {
                float g = u.s.pb.grp2[bucket * GSTRIDE + j];
                c_in += (g < h);
                eq += (g == h);
            }
        }
        f = dpp_scan_add(u.s.pb.hist[t]);           // wave scan (VALU)
        if (lane == 63) s_wsum[w] = f;
        __syncthreads();                                    // B4
        {   // all-wave redundant exclusive wave base -> register
            int vv = ((lane & 15) < w) ? s_wsum[lane & 15] : 0;
            vv = dpp_red16_add(vv);
            u.s.pb.scan[t] = f + vv;
        }
        u.s.pb.hist[t] = 0;             // readers latched cnt pre-B4
        if (t == 0) s_ovf = 0;          // readers latched ovf pre-B4
        __syncthreads();                                    // B6

        int cr;
        if (!ovf) {
            cr = (u.s.pb.scan[bucket] - cnt) + c_in;    // dense rank iff no ties
        } else {                        // slow path: scan-ordered groups
            int bs = u.s.pb.scan[bucket] - cnt;
            u.s.pb.grp[bs + off_in] = h;
            __syncthreads();                                // B7 (rare)
            cr = bs;
            eq = 0;
            for (int k = bs; k < bs + cnt; ++k) {
                float g = u.s.pb.grp[k];
                cr += (g < h);
                eq += (g == h);
            }
        }
        if (eq > 1) s_anytie = it + 1;  // sentinel: stale iters self-invalidate
        s_lab[t] = cr;                  // optimistic fast-path rank
        __syncthreads();                                    // B9
        if (s_anytie == it + 1) {       // rare: dense-rank repair pass
            u.s.pb.flag[cr] = 1;        // class start (same class -> same cr)
            __syncthreads();                                // T1
            int f2 = dpp_scan_add(u.s.pb.flag[t]);
            if (lane == 63) s_wsum[w] = f2;
            __syncthreads();                                // T2
            {   // all-wave redundant exclusive wave base -> register
                int vv = ((lane & 15) < w) ? s_wsum[lane & 15] : 0;
                vv = dpp_red16_add(vv);
                u.s.pb.scan[t] = f2 + vv;
            }
            u.s.pb.flag[t] = 0;         // own flag consumed above
            __syncthreads();                                // T4
            int rank = u.s.pb.scan[cr] - 1;
            s_lab[t] = rank;
            lab_reg = rank;
            atomicAdd(&s_feats[rank], 1u);
            __syncthreads();                                // T5: labels visible
        } else {
            lab_reg = cr;
            ++nfast;                    // permutation => every bin +1
        }
    }

    // ---- Phase C: feats out + fused diag[b] (int exact) ----
    unsigned int fv = s_feats[t] + (unsigned)nfast;
    feats[(size_t)b * N + t] = fv;
    int sq = dpp_scan_add((int)(fv * fv));
    if (lane == 63) s_wsum[w] = sq;
    __syncthreads();
    if (t == 0) {
        int tot = 0;
#pragma unroll
        for (int k = 0; k < 16; ++k) tot += s_wsum[k];
        diag[b] = (float)tot;
    }
}

// gram+normalize fused: one block per row i; f_i staged in LDS; int dots
// exact. 1024 threads, 16 waves x 4 j's each; DPP scan-sum, lane63 stores.
__global__ void __launch_bounds__(1024) gram_k(const unsigned int* __restrict__ feats,
                                               const float* __restrict__ diag,
                                               float* __restrict__ out) {
    __shared__ unsigned int s_fi[N];
    int i = blockIdx.x, t = threadIdx.x;
    int lane = t & 63, w = t >> 6;
    if (t < 256)
        ((uint4*)s_fi)[t] = ((const uint4*)(feats + (size_t)i * N))[t];
    __syncthreads();
    float di = diag[i];
#pragma unroll
    for (int jj = 0; jj < 4; ++jj) {
        int j = w * 4 + jj;
        const uint4* fj = (const uint4*)(feats + (size_t)j * N);
        const uint4* fi = (const uint4*)s_fi;
        int s = 0;
#pragma unroll
        for (int k = 0; k < 4; ++k) {
            uint4 vb = fj[lane + k * 64];
            uint4 va = fi[lane + k * 64];
            s += (int)(va.x * vb.x) + (int)(va.y * vb.y)
               + (int)(va.z * vb.z) + (int)(va.w * vb.w);
        }
        s = dpp_scan_add(s);
        if (lane == 63) out[i * B + j] = (float)s / sqrtf(di * diag[j]);
    }
}

extern "C" void kernel_launch(void* const* d_in, const int* in_sizes, int n_in,
                              void* d_out, int out_size, void* d_ws, size_t ws_size,
                              hipStream_t stream) {
    const int*   esrc = (const int*)d_in[0];
    const int*   edst = (const int*)d_in[1];
    const int*   lab0 = (const int*)d_in[2];
    const float* hw   = (const float*)d_in[3];

    char* ws = (char*)d_ws;
    unsigned int* feats = (unsigned int*)(ws + FEATS_OFF);
    float*        diag  = (float*)(ws + DIAG_OFF);

    wl_mega_k<<<B, 1024, 0, stream>>>(esrc, edst, lab0, hw, feats, diag);
    gram_k<<<B, 1024, 0, stream>>>(feats, diag, (float*)d_out);
}